// Round 1
// baseline (110.153 us; speedup 1.0000x reference)
//
#include <hip/hip_runtime.h>
#include <math.h>

// Problem constants
#define BATCH 4
#define NPTS  2048
#define NT    256
#define COLCHUNK 512

// Workspace layout (float units unless noted)
// Padded point arrays: float4 (x,y,z,sqnorm), BATCH*NPTS entries each
#define F4N        (BATCH * NPTS)            // 8192 float4 per array
#define OFF_PT0    0                          // P_t0
#define OFF_PT1    (F4N * 4)                  // P_t1       @ 32768 floats
#define OFF_PT1H   (F4N * 8)                  // P_t1_hat   @ 65536
#define OFF_PY0    (F4N * 12)                 // P_y0       @ 98304
#define OFF_DIST1  (F4N * 16)                 // dist1 [B*N] @ 131072
#define OFF_DIST2  (OFF_DIST1 + F4N)          // dist2
#define OFF_C1     (OFF_DIST1 + 2 * F4N)      // c1
#define OFF_RM3    (OFF_DIST1 + 3 * F4N)      // rowmin y0->x_t1
#define OFF_RM2    (OFF_DIST1 + 4 * F4N)      // packed u64 [B*N] @ 163840 floats (8B aligned)
#define OFF_MASKC  (OFF_RM2 + 2 * F4N)        // mask_chamfer [B] @ 180224
#define OFF_ACCUM  (OFF_MASKC + 4)            // [ld_num, ld_cnt, dyn_sum, stat_sum]

#define INF_BITS 0x7f800000u

__device__ __forceinline__ float sqnorm3(float x, float y, float z) {
    // mimic jnp.sum(a*a, -1): squares then left-assoc add chain, no fma contraction
    return __fadd_rn(__fadd_rn(__fmul_rn(x, x), __fmul_rn(y, y)), __fmul_rn(z, z));
}

// ---------------------------------------------------------------- prep
__global__ __launch_bounds__(NT) void prep_kernel(
    const float* __restrict__ x, const float* __restrict__ m_hat,
    const float* __restrict__ y_hat0, float* __restrict__ ws)
{
    int gid = blockIdx.x * NT + threadIdx.x;       // 0 .. B*N-1
    int b = gid >> 11, n = gid & (NPTS - 1);

    const float* xt0 = x + ((size_t)(b * 2 + 0) * NPTS + n) * 3;
    const float* xt1 = x + ((size_t)(b * 2 + 1) * NPTS + n) * 3;
    const float* mh  = m_hat  + ((size_t)b * NPTS + n) * 3;
    const float* yy  = y_hat0 + ((size_t)b * NPTS + n) * 3;

    float a0 = xt0[0], a1 = xt0[1], a2 = xt0[2];
    float c0 = xt1[0], c1v = xt1[1], c2 = xt1[2];
    float h0 = a0 + mh[0], h1 = a1 + mh[1], h2 = a2 + mh[2];
    float y0 = yy[0], y1 = yy[1], y2 = yy[2];

    float4* P = (float4*)ws;
    P[(OFF_PT0  >> 2) + gid] = make_float4(a0, a1, a2, sqnorm3(a0, a1, a2));
    P[(OFF_PT1  >> 2) + gid] = make_float4(c0, c1v, c2, sqnorm3(c0, c1v, c2));
    P[(OFF_PT1H >> 2) + gid] = make_float4(h0, h1, h2, sqnorm3(h0, h1, h2));
    P[(OFF_PY0  >> 2) + gid] = make_float4(y0, y1, y2, sqnorm3(y0, y1, y2));

    unsigned* u = (unsigned*)ws;
    u[OFF_DIST1 + gid] = INF_BITS;
    u[OFF_DIST2 + gid] = INF_BITS;
    u[OFF_C1    + gid] = INF_BITS;
    u[OFF_RM3   + gid] = INF_BITS;
    ((unsigned long long*)(ws + OFF_RM2))[gid] = 0xFFFFFFFFFFFFFFFFull;

    if (gid < 4) ws[OFF_ACCUM + gid] = 0.0f;
}

// ---------------------------------------------------------------- pairwise
// grid: x = rowBlock(8) * colChunk(4) -> 32, y = batch(4), z = problem(5)
__global__ __launch_bounds__(NT) void pairwise_kernel(float* __restrict__ ws)
{
    int tid = threadIdx.x;
    int rowBlk   = blockIdx.x >> 2;
    int colChunk = blockIdx.x & 3;
    int b    = blockIdx.y;
    int prob = blockIdx.z;

    const float4* P = (const float4*)ws;
    const float4* rows;
    const float4* cols;
    float* out = nullptr;

    switch (prob) {
        case 0: rows = P + (OFF_PT1H >> 2); cols = P + (OFF_PT1  >> 2); out = ws + OFF_DIST1; break;
        case 1: rows = P + (OFF_PT1  >> 2); cols = P + (OFF_PT1H >> 2); out = ws + OFF_DIST2; break;
        case 2: rows = P + (OFF_PY0  >> 2); cols = P + (OFF_PT0  >> 2); break; // argmin path
        case 3: rows = P + (OFF_PY0  >> 2); cols = P + (OFF_PT1  >> 2); out = ws + OFF_RM3;   break;
        default: rows = P + (OFF_PT0 >> 2); cols = P + (OFF_PY0  >> 2); out = ws + OFF_C1;    break;
    }

    int r = rowBlk * NT + tid;
    float4 a = rows[b * NPTS + r];
    const float4* cp = cols + b * NPTS + colChunk * COLCHUNK;

    float best = __uint_as_float(INF_BITS);

    if (prob == 2) {
        int bestIdx = 0;
        #pragma unroll 8
        for (int c = 0; c < COLCHUNK; ++c) {
            float4 q = cp[c];
            float dot = a.x * q.x + a.y * q.y + a.z * q.z;           // fma chain, like einsum
            float d = __fsub_rn(__fadd_rn(a.w, q.w), __fmul_rn(2.0f, dot));
            d = fmaxf(d, 0.0f);
            if (d < best) { best = d; bestIdx = c; }                  // first-occurrence
        }
        unsigned long long key =
            ((unsigned long long)__float_as_uint(best) << 32) |
            (unsigned)(colChunk * COLCHUNK + bestIdx);
        atomicMin(((unsigned long long*)(ws + OFF_RM2)) + (size_t)b * NPTS + r, key);
    } else {
        #pragma unroll 8
        for (int c = 0; c < COLCHUNK; ++c) {
            float4 q = cp[c];
            float dot = a.x * q.x + a.y * q.y + a.z * q.z;
            float d = __fsub_rn(__fadd_rn(a.w, q.w), __fmul_rn(2.0f, dot));
            d = fmaxf(d, 0.0f);
            best = fminf(best, d);
        }
        atomicMin((unsigned*)(out + (size_t)b * NPTS + r), __float_as_uint(best));
    }
}

// ---------------------------------------------------------------- per-batch reduce
// grid: BATCH blocks of NT threads
__global__ __launch_bounds__(NT) void reduce_kernel(float* __restrict__ ws)
{
    int b = blockIdx.x, tid = threadIdx.x;
    const float* dist1 = ws + OFF_DIST1 + (size_t)b * NPTS;
    const float* dist2 = ws + OFF_DIST2 + (size_t)b * NPTS;
    const float* c1    = ws + OFF_C1    + (size_t)b * NPTS;

    float s1 = 0.f, s2 = 0.f, cs = 0.f, cc = 0.f;
    for (int i = tid; i < NPTS; i += NT) {
        s1 += dist1[i];
        s2 += dist2[i];
        float c = c1[i];
        if (c < 0.1f) { cs += c; cc += 1.0f; }
    }
    #pragma unroll
    for (int off = 32; off > 0; off >>= 1) {
        s1 += __shfl_down(s1, off);
        s2 += __shfl_down(s2, off);
        cs += __shfl_down(cs, off);
        cc += __shfl_down(cc, off);
    }
    __shared__ float sm[4][4];
    int wv = tid >> 6, ln = tid & 63;
    if (ln == 0) { sm[wv][0] = s1; sm[wv][1] = s2; sm[wv][2] = cs; sm[wv][3] = cc; }
    __syncthreads();
    if (tid == 0) {
        float t1 = sm[0][0] + sm[1][0] + sm[2][0] + sm[3][0];
        float t2 = sm[0][1] + sm[1][1] + sm[2][1] + sm[3][1];
        float tc = sm[0][2] + sm[1][2] + sm[2][2] + sm[3][2];
        float tn = sm[0][3] + sm[1][3] + sm[2][3] + sm[3][3];
        float loss_chamfer = t1 / (float)NPTS + t2 / (float)NPTS;
        ws[OFF_MASKC + b] = (loss_chamfer < 0.1f) ? 1.0f : 0.0f;
        atomicAdd(ws + OFF_ACCUM + 0, tc);  // loss_dist numerator
        atomicAdd(ws + OFF_ACCUM + 1, tn);  // loss_dist count
    }
}

// ---------------------------------------------------------------- finalize (per y0 point)
__global__ __launch_bounds__(NT) void finalize_kernel(
    const float* __restrict__ m_hat, const float* __restrict__ y_hat0,
    const float* __restrict__ y_hat1, float* __restrict__ ws)
{
    int gid = blockIdx.x * NT + threadIdx.x;   // 0 .. B*M-1
    int b = gid >> 11, m = gid & (NPTS - 1);

    unsigned long long key = ((const unsigned long long*)(ws + OFF_RM2))[gid];
    float d2 = __uint_as_float((unsigned)(key >> 32));
    unsigned idx = (unsigned)(key & 0xFFFFFFFFull);
    float rm3 = ws[OFF_RM3 + gid];

    float md   = (sqrtf(d2) < 0.05f) ? 1.0f : 0.0f;
    float dcat = fminf(d2, rm3);
    float mneg = (sqrtf(dcat) > 0.2f) ? 1.0f : 0.0f;
    float w = ws[OFF_MASKC + b] * md;

    const float* p0 = y_hat0 + (size_t)gid * 3;
    const float* p1 = y_hat1 + (size_t)gid * 3;
    const float* nm = m_hat + ((size_t)b * NPTS + idx) * 3;

    float dyn = 0.f, stat = 0.f;
    #pragma unroll
    for (int k = 0; k < 3; ++k) {
        float diff = p1[k] - p0[k];
        float e = w * (diff - nm[k]);      // pred - tgt with 0/1 masks
        dyn += e * e;
        float s = mneg * diff;
        stat += s * s;
    }
    #pragma unroll
    for (int off = 32; off > 0; off >>= 1) {
        dyn  += __shfl_down(dyn, off);
        stat += __shfl_down(stat, off);
    }
    __shared__ float sd[4], ss[4];
    int wv = threadIdx.x >> 6, ln = threadIdx.x & 63;
    if (ln == 0) { sd[wv] = dyn; ss[wv] = stat; }
    __syncthreads();
    if (threadIdx.x == 0) {
        atomicAdd(ws + OFF_ACCUM + 2, sd[0] + sd[1] + sd[2] + sd[3]);
        atomicAdd(ws + OFF_ACCUM + 3, ss[0] + ss[1] + ss[2] + ss[3]);
    }
}

// ---------------------------------------------------------------- writeout
__global__ void writeout_kernel(const float* __restrict__ ws, float* __restrict__ out)
{
    const float denom = (float)(BATCH * NPTS * 3);   // 24576
    out[0] = ws[OFF_ACCUM + 2] / denom;                       // loss_dynamic
    out[1] = ws[OFF_ACCUM + 3] / denom;                       // loss_static
    out[2] = ws[OFF_ACCUM + 0] / fmaxf(ws[OFF_ACCUM + 1], 1.0f);  // loss_dist
}

extern "C" void kernel_launch(void* const* d_in, const int* in_sizes, int n_in,
                              void* d_out, int out_size, void* d_ws, size_t ws_size,
                              hipStream_t stream)
{
    const float* x      = (const float*)d_in[0];
    const float* m_hat  = (const float*)d_in[1];
    const float* y_hat0 = (const float*)d_in[2];
    const float* y_hat1 = (const float*)d_in[3];
    float* ws  = (float*)d_ws;
    float* out = (float*)d_out;

    prep_kernel<<<dim3((BATCH * NPTS) / NT), dim3(NT), 0, stream>>>(x, m_hat, y_hat0, ws);
    pairwise_kernel<<<dim3(32, BATCH, 5), dim3(NT), 0, stream>>>(ws);
    reduce_kernel<<<dim3(BATCH), dim3(NT), 0, stream>>>(ws);
    finalize_kernel<<<dim3((BATCH * NPTS) / NT), dim3(NT), 0, stream>>>(m_hat, y_hat0, y_hat1, ws);
    writeout_kernel<<<dim3(1), dim3(1), 0, stream>>>(ws, out);
}

// Round 2
// 86.477 us; speedup vs baseline: 1.2738x; 1.2738x over previous
//
#include <hip/hip_runtime.h>
#include <math.h>

// Problem constants
#define BATCH 4
#define NPTS  2048
#define NT    256
#define ROWS_PT 4          // rows per thread in pairwise
#define CPB     64         // columns per block in pairwise
#define COLCHUNKS (NPTS / CPB)   // 32
#define ROWHALVES 2              // 2048 / (NT*ROWS_PT)

// Workspace layout (float units unless noted)
#define F4N        (BATCH * NPTS)            // 8192 float4 per array
#define OFF_PT0    0
#define OFF_PT1    (F4N * 4)
#define OFF_PT1H   (F4N * 8)
#define OFF_PY0    (F4N * 12)
#define OFF_DIST1  (F4N * 16)
#define OFF_DIST2  (OFF_DIST1 + F4N)
#define OFF_C1     (OFF_DIST1 + 2 * F4N)
#define OFF_RM3    (OFF_DIST1 + 3 * F4N)
#define OFF_RM2    (OFF_DIST1 + 4 * F4N)      // u64 packed, 8B aligned
#define OFF_MASKC  (OFF_RM2 + 2 * F4N)
#define OFF_ACCUM  (OFF_MASKC + 4)

#define INF_BITS 0x7f800000u

__device__ __forceinline__ float sqnorm3(float x, float y, float z) {
    // mimic jnp.sum(a*a, -1): squares then left-assoc add chain, no fma contraction
    return __fadd_rn(__fadd_rn(__fmul_rn(x, x), __fmul_rn(y, y)), __fmul_rn(z, z));
}

// ---------------------------------------------------------------- prep
__global__ __launch_bounds__(NT) void prep_kernel(
    const float* __restrict__ x, const float* __restrict__ m_hat,
    const float* __restrict__ y_hat0, float* __restrict__ ws)
{
    int gid = blockIdx.x * NT + threadIdx.x;       // 0 .. B*N-1
    int b = gid >> 11, n = gid & (NPTS - 1);

    const float* xt0 = x + ((size_t)(b * 2 + 0) * NPTS + n) * 3;
    const float* xt1 = x + ((size_t)(b * 2 + 1) * NPTS + n) * 3;
    const float* mh  = m_hat  + ((size_t)b * NPTS + n) * 3;
    const float* yy  = y_hat0 + ((size_t)b * NPTS + n) * 3;

    float a0 = xt0[0], a1 = xt0[1], a2 = xt0[2];
    float c0 = xt1[0], c1v = xt1[1], c2 = xt1[2];
    float h0 = a0 + mh[0], h1 = a1 + mh[1], h2 = a2 + mh[2];
    float y0 = yy[0], y1 = yy[1], y2 = yy[2];

    float4* P = (float4*)ws;
    P[(OFF_PT0  >> 2) + gid] = make_float4(a0, a1, a2, sqnorm3(a0, a1, a2));
    P[(OFF_PT1  >> 2) + gid] = make_float4(c0, c1v, c2, sqnorm3(c0, c1v, c2));
    P[(OFF_PT1H >> 2) + gid] = make_float4(h0, h1, h2, sqnorm3(h0, h1, h2));
    P[(OFF_PY0  >> 2) + gid] = make_float4(y0, y1, y2, sqnorm3(y0, y1, y2));

    unsigned* u = (unsigned*)ws;
    u[OFF_DIST1 + gid] = INF_BITS;
    u[OFF_DIST2 + gid] = INF_BITS;
    u[OFF_C1    + gid] = INF_BITS;
    u[OFF_RM3   + gid] = INF_BITS;
    ((unsigned long long*)(ws + OFF_RM2))[gid] = 0xFFFFFFFFFFFFFFFFull;

    if (gid < 4) ws[OFF_ACCUM + gid] = 0.0f;
}

// ---------------------------------------------------------------- pairwise
// grid: x = rowHalf(2)*colChunk(32) -> 64, y = batch(4), z = problem(5)
// Each thread: ROWS_PT=4 rows (r0 + k*256), CPB=64 columns staged in LDS.
// 1280 blocks = 5 blocks/CU exactly; 4 independent fmin chains per thread.
__global__ __launch_bounds__(NT) void pairwise_kernel(float* __restrict__ ws)
{
    __shared__ float4 tile[CPB];

    int tid = threadIdx.x;
    int rowHalf  = blockIdx.x >> 5;
    int colChunk = blockIdx.x & 31;
    int b    = blockIdx.y;
    int prob = blockIdx.z;

    const float4* P = (const float4*)ws;
    const float4* rows;
    const float4* cols;
    float* out = nullptr;

    switch (prob) {
        case 0: rows = P + (OFF_PT1H >> 2); cols = P + (OFF_PT1  >> 2); out = ws + OFF_DIST1; break;
        case 1: rows = P + (OFF_PT1  >> 2); cols = P + (OFF_PT1H >> 2); out = ws + OFF_DIST2; break;
        case 2: rows = P + (OFF_PY0  >> 2); cols = P + (OFF_PT0  >> 2); break; // argmin path
        case 3: rows = P + (OFF_PY0  >> 2); cols = P + (OFF_PT1  >> 2); out = ws + OFF_RM3;   break;
        default: rows = P + (OFF_PT0 >> 2); cols = P + (OFF_PY0  >> 2); out = ws + OFF_C1;    break;
    }

    int colBase = colChunk * CPB;
    if (tid < CPB) tile[tid] = cols[(size_t)b * NPTS + colBase + tid];

    int r0 = rowHalf * (NT * ROWS_PT) + tid;     // rows r0 + k*NT
    float4 a[ROWS_PT];
    #pragma unroll
    for (int k = 0; k < ROWS_PT; ++k)
        a[k] = rows[(size_t)b * NPTS + r0 + k * NT];

    __syncthreads();

    if (prob == 2) {
        float best[ROWS_PT];
        int bestIdx[ROWS_PT];
        #pragma unroll
        for (int k = 0; k < ROWS_PT; ++k) { best[k] = __uint_as_float(INF_BITS); bestIdx[k] = 0; }
        #pragma unroll 4
        for (int c = 0; c < CPB; ++c) {
            float4 q = tile[c];
            #pragma unroll
            for (int k = 0; k < ROWS_PT; ++k) {
                float dot = a[k].x * q.x + a[k].y * q.y + a[k].z * q.z;   // fma chain
                float d = __fsub_rn(__fadd_rn(a[k].w, q.w), __fmul_rn(2.0f, dot));
                d = fmaxf(d, 0.0f);
                if (d < best[k]) { best[k] = d; bestIdx[k] = c; }          // first-occurrence
            }
        }
        #pragma unroll
        for (int k = 0; k < ROWS_PT; ++k) {
            unsigned long long key =
                ((unsigned long long)__float_as_uint(best[k]) << 32) |
                (unsigned)(colBase + bestIdx[k]);
            atomicMin(((unsigned long long*)(ws + OFF_RM2)) + (size_t)b * NPTS + r0 + k * NT, key);
        }
    } else {
        float best[ROWS_PT];
        #pragma unroll
        for (int k = 0; k < ROWS_PT; ++k) best[k] = __uint_as_float(INF_BITS);
        #pragma unroll 4
        for (int c = 0; c < CPB; ++c) {
            float4 q = tile[c];
            #pragma unroll
            for (int k = 0; k < ROWS_PT; ++k) {
                float dot = a[k].x * q.x + a[k].y * q.y + a[k].z * q.z;
                float d = __fsub_rn(__fadd_rn(a[k].w, q.w), __fmul_rn(2.0f, dot));
                d = fmaxf(d, 0.0f);
                best[k] = fminf(best[k], d);
            }
        }
        #pragma unroll
        for (int k = 0; k < ROWS_PT; ++k)
            atomicMin((unsigned*)(out + (size_t)b * NPTS + r0 + k * NT), __float_as_uint(best[k]));
    }
}

// ---------------------------------------------------------------- per-batch reduce
__global__ __launch_bounds__(NT) void reduce_kernel(float* __restrict__ ws)
{
    int b = blockIdx.x, tid = threadIdx.x;
    const float* dist1 = ws + OFF_DIST1 + (size_t)b * NPTS;
    const float* dist2 = ws + OFF_DIST2 + (size_t)b * NPTS;
    const float* c1    = ws + OFF_C1    + (size_t)b * NPTS;

    float s1 = 0.f, s2 = 0.f, cs = 0.f, cc = 0.f;
    for (int i = tid; i < NPTS; i += NT) {
        s1 += dist1[i];
        s2 += dist2[i];
        float c = c1[i];
        if (c < 0.1f) { cs += c; cc += 1.0f; }
    }
    #pragma unroll
    for (int off = 32; off > 0; off >>= 1) {
        s1 += __shfl_down(s1, off);
        s2 += __shfl_down(s2, off);
        cs += __shfl_down(cs, off);
        cc += __shfl_down(cc, off);
    }
    __shared__ float sm[4][4];
    int wv = tid >> 6, ln = tid & 63;
    if (ln == 0) { sm[wv][0] = s1; sm[wv][1] = s2; sm[wv][2] = cs; sm[wv][3] = cc; }
    __syncthreads();
    if (tid == 0) {
        float t1 = sm[0][0] + sm[1][0] + sm[2][0] + sm[3][0];
        float t2 = sm[0][1] + sm[1][1] + sm[2][1] + sm[3][1];
        float tc = sm[0][2] + sm[1][2] + sm[2][2] + sm[3][2];
        float tn = sm[0][3] + sm[1][3] + sm[2][3] + sm[3][3];
        float loss_chamfer = t1 / (float)NPTS + t2 / (float)NPTS;
        ws[OFF_MASKC + b] = (loss_chamfer < 0.1f) ? 1.0f : 0.0f;
        atomicAdd(ws + OFF_ACCUM + 0, tc);  // loss_dist numerator
        atomicAdd(ws + OFF_ACCUM + 1, tn);  // loss_dist count
    }
}

// ---------------------------------------------------------------- finalize (per y0 point)
__global__ __launch_bounds__(NT) void finalize_kernel(
    const float* __restrict__ m_hat, const float* __restrict__ y_hat0,
    const float* __restrict__ y_hat1, float* __restrict__ ws)
{
    int gid = blockIdx.x * NT + threadIdx.x;   // 0 .. B*M-1
    int b = gid >> 11;

    unsigned long long key = ((const unsigned long long*)(ws + OFF_RM2))[gid];
    float d2 = __uint_as_float((unsigned)(key >> 32));
    unsigned idx = (unsigned)(key & 0xFFFFFFFFull);
    float rm3 = ws[OFF_RM3 + gid];

    float md   = (sqrtf(d2) < 0.05f) ? 1.0f : 0.0f;
    float dcat = fminf(d2, rm3);
    float mneg = (sqrtf(dcat) > 0.2f) ? 1.0f : 0.0f;
    float w = ws[OFF_MASKC + b] * md;

    const float* p0 = y_hat0 + (size_t)gid * 3;
    const float* p1 = y_hat1 + (size_t)gid * 3;
    const float* nm = m_hat + ((size_t)b * NPTS + idx) * 3;

    float dyn = 0.f, stat = 0.f;
    #pragma unroll
    for (int k = 0; k < 3; ++k) {
        float diff = p1[k] - p0[k];
        float e = w * (diff - nm[k]);      // pred - tgt with 0/1 masks
        dyn += e * e;
        float s = mneg * diff;
        stat += s * s;
    }
    #pragma unroll
    for (int off = 32; off > 0; off >>= 1) {
        dyn  += __shfl_down(dyn, off);
        stat += __shfl_down(stat, off);
    }
    __shared__ float sd[4], ss[4];
    int wv = threadIdx.x >> 6, ln = threadIdx.x & 63;
    if (ln == 0) { sd[wv] = dyn; ss[wv] = stat; }
    __syncthreads();
    if (threadIdx.x == 0) {
        atomicAdd(ws + OFF_ACCUM + 2, sd[0] + sd[1] + sd[2] + sd[3]);
        atomicAdd(ws + OFF_ACCUM + 3, ss[0] + ss[1] + ss[2] + ss[3]);
    }
}

// ---------------------------------------------------------------- writeout
__global__ void writeout_kernel(const float* __restrict__ ws, float* __restrict__ out)
{
    const float denom = (float)(BATCH * NPTS * 3);   // 24576
    out[0] = ws[OFF_ACCUM + 2] / denom;                       // loss_dynamic
    out[1] = ws[OFF_ACCUM + 3] / denom;                       // loss_static
    out[2] = ws[OFF_ACCUM + 0] / fmaxf(ws[OFF_ACCUM + 1], 1.0f);  // loss_dist
}

extern "C" void kernel_launch(void* const* d_in, const int* in_sizes, int n_in,
                              void* d_out, int out_size, void* d_ws, size_t ws_size,
                              hipStream_t stream)
{
    const float* x      = (const float*)d_in[0];
    const float* m_hat  = (const float*)d_in[1];
    const float* y_hat0 = (const float*)d_in[2];
    const float* y_hat1 = (const float*)d_in[3];
    float* ws  = (float*)d_ws;
    float* out = (float*)d_out;

    prep_kernel<<<dim3((BATCH * NPTS) / NT), dim3(NT), 0, stream>>>(x, m_hat, y_hat0, ws);
    pairwise_kernel<<<dim3(ROWHALVES * COLCHUNKS, BATCH, 5), dim3(NT), 0, stream>>>(ws);
    reduce_kernel<<<dim3(BATCH), dim3(NT), 0, stream>>>(ws);
    finalize_kernel<<<dim3((BATCH * NPTS) / NT), dim3(NT), 0, stream>>>(m_hat, y_hat0, y_hat1, ws);
    writeout_kernel<<<dim3(1), dim3(1), 0, stream>>>(ws, out);
}

// Round 3
// 86.426 us; speedup vs baseline: 1.2745x; 1.0006x over previous
//
#include <hip/hip_runtime.h>
#include <math.h>

// Problem constants
#define BATCH 4
#define NPTS  2048
#define NT    256
#define ROWS_PT 4                 // rows per thread in pairwise
#define CPB     64                // columns per block in pairwise
#define COLCHUNKS (NPTS / CPB)    // 32
#define ROWHALVES 2               // 2048 / (NT*ROWS_PT)
#define ROWS_TOT  (BATCH * NPTS)  // 8192

// Workspace layout (float units). All regions written unconditionally before
// being read -> no init needed despite 0xAA poison. No atomics anywhere.
#define OFF_PD1   0                        // [32][8192] f : chunk-partial min, dist1
#define OFF_PD2   (COLCHUNKS * ROWS_TOT)           // dist2
#define OFF_PC1   (2 * COLCHUNKS * ROWS_TOT)       // c1
#define OFF_PRM3  (3 * COLCHUNKS * ROWS_TOT)       // rowmin y0->x_t1
#define OFF_PRM2  (4 * COLCHUNKS * ROWS_TOT)       // [32][8192] u64 packed (min,argmin)
#define OFF_BLK   (6 * COLCHUNKS * ROWS_TOT)       // [64][8] f per-block partial sums

#define INF_BITS 0x7f800000u

typedef unsigned long long ull;

__device__ __forceinline__ float sqnorm3(float x, float y, float z) {
    // mimic jnp.sum(a*a, -1): squares then left-assoc add chain, no fma contraction
    return __fadd_rn(__fadd_rn(__fmul_rn(x, x), __fmul_rn(y, y)), __fmul_rn(z, z));
}

// point sources
#define SRC_T0  0
#define SRC_T1  1
#define SRC_T1H 2
#define SRC_Y0  3

__device__ __forceinline__ float4 make_point(int src, int b, int i,
    const float* __restrict__ x, const float* __restrict__ m_hat,
    const float* __restrict__ y_hat0)
{
    float px, py, pz;
    if (src == SRC_Y0) {
        const float* p = y_hat0 + ((size_t)b * NPTS + i) * 3;
        px = p[0]; py = p[1]; pz = p[2];
    } else if (src == SRC_T1) {
        const float* p = x + ((size_t)(b * 2 + 1) * NPTS + i) * 3;
        px = p[0]; py = p[1]; pz = p[2];
    } else {
        const float* p = x + ((size_t)(b * 2 + 0) * NPTS + i) * 3;
        px = p[0]; py = p[1]; pz = p[2];
        if (src == SRC_T1H) {           // x_t0 + m_hat (same op order as before)
            const float* mh = m_hat + ((size_t)b * NPTS + i) * 3;
            px += mh[0]; py += mh[1]; pz += mh[2];
        }
    }
    return make_float4(px, py, pz, sqnorm3(px, py, pz));
}

__device__ __forceinline__ ull shfl_xor_u64(ull v, int m) {
    int lo = __shfl_xor((int)(v & 0xFFFFFFFFull), m);
    int hi = __shfl_xor((int)(v >> 32), m);
    return ((ull)(unsigned)hi << 32) | (unsigned)lo;
}

// ---------------------------------------------------------------- pairwise
// grid: x = rowHalf(2)*colChunk(32) -> 64, y = batch(4), z = problem(5)
// 1280 blocks = 5 blocks/CU. Inline prep from raw inputs; partial-slot writes.
__global__ __launch_bounds__(NT) void pairwise_kernel(
    const float* __restrict__ x, const float* __restrict__ m_hat,
    const float* __restrict__ y_hat0, float* __restrict__ ws)
{
    __shared__ float4 tile[CPB];

    int tid = threadIdx.x;
    int rowHalf  = blockIdx.x >> 5;
    int colChunk = blockIdx.x & 31;
    int b    = blockIdx.y;
    int prob = blockIdx.z;

    int rsrc, csrc, outOff;
    switch (prob) {
        case 0:  rsrc = SRC_T1H; csrc = SRC_T1;  outOff = OFF_PD1;  break;
        case 1:  rsrc = SRC_T1;  csrc = SRC_T1H; outOff = OFF_PD2;  break;
        case 2:  rsrc = SRC_Y0;  csrc = SRC_T0;  outOff = -1;       break; // argmin path
        case 3:  rsrc = SRC_Y0;  csrc = SRC_T1;  outOff = OFF_PRM3; break;
        default: rsrc = SRC_T0;  csrc = SRC_Y0;  outOff = OFF_PC1;  break;
    }

    int colBase = colChunk * CPB;
    if (tid < CPB) tile[tid] = make_point(csrc, b, colBase + tid, x, m_hat, y_hat0);

    int r0 = rowHalf * (NT * ROWS_PT) + tid;
    float4 a[ROWS_PT];
    #pragma unroll
    for (int k = 0; k < ROWS_PT; ++k)
        a[k] = make_point(rsrc, b, r0 + k * NT, x, m_hat, y_hat0);

    __syncthreads();

    if (prob == 2) {
        float best[ROWS_PT];
        int bestIdx[ROWS_PT];
        #pragma unroll
        for (int k = 0; k < ROWS_PT; ++k) { best[k] = __uint_as_float(INF_BITS); bestIdx[k] = 0; }
        #pragma unroll 4
        for (int c = 0; c < CPB; ++c) {
            float4 q = tile[c];
            #pragma unroll
            for (int k = 0; k < ROWS_PT; ++k) {
                float dot = a[k].x * q.x + a[k].y * q.y + a[k].z * q.z;   // fma chain
                float d = __fsub_rn(__fadd_rn(a[k].w, q.w), __fmul_rn(2.0f, dot));
                d = fmaxf(d, 0.0f);
                if (d < best[k]) { best[k] = d; bestIdx[k] = c; }          // first-occurrence
            }
        }
        ull* prm2 = (ull*)(ws + OFF_PRM2);
        #pragma unroll
        for (int k = 0; k < ROWS_PT; ++k) {
            ull key = ((ull)__float_as_uint(best[k]) << 32) |
                      (unsigned)(colBase + bestIdx[k]);
            prm2[(size_t)colChunk * ROWS_TOT + b * NPTS + r0 + k * NT] = key;
        }
    } else {
        float best[ROWS_PT];
        #pragma unroll
        for (int k = 0; k < ROWS_PT; ++k) best[k] = __uint_as_float(INF_BITS);
        #pragma unroll 4
        for (int c = 0; c < CPB; ++c) {
            float4 q = tile[c];
            #pragma unroll
            for (int k = 0; k < ROWS_PT; ++k) {
                float dot = a[k].x * q.x + a[k].y * q.y + a[k].z * q.z;
                float d = __fsub_rn(__fadd_rn(a[k].w, q.w), __fmul_rn(2.0f, dot));
                d = fmaxf(d, 0.0f);
                best[k] = fminf(best[k], d);
            }
        }
        #pragma unroll
        for (int k = 0; k < ROWS_PT; ++k)
            ws[outOff + (size_t)colChunk * ROWS_TOT + b * NPTS + r0 + k * NT] = best[k];
    }
}

// ---------------------------------------------------------------- row reduce + finalize
// grid: 64 blocks x 256. 2 threads per row (16 chunks each), shfl_xor combine,
// then per-row finalize math; 6 per-block partial sums -> OFF_BLK (no atomics).
__global__ __launch_bounds__(NT) void rowreduce_kernel(
    const float* __restrict__ m_hat, const float* __restrict__ y_hat0,
    const float* __restrict__ y_hat1, float* __restrict__ ws)
{
    int tid  = threadIdx.x;
    int row  = blockIdx.x * 128 + (tid >> 1);   // [0, 8192)
    int half = tid & 1;
    int b    = row >> 11;

    const ull* prm2 = (const ull*)(ws + OFF_PRM2);

    float d1m = __uint_as_float(INF_BITS), d2m = d1m, c1m = d1m, r3m = d1m;
    ull k2 = ~0ull;
    #pragma unroll
    for (int c = 0; c < 16; ++c) {
        int idx = (half * 16 + c) * ROWS_TOT + row;
        d1m = fminf(d1m, ws[OFF_PD1 + idx]);
        d2m = fminf(d2m, ws[OFF_PD2 + idx]);
        c1m = fminf(c1m, ws[OFF_PC1 + idx]);
        r3m = fminf(r3m, ws[OFF_PRM3 + idx]);
        ull kk = prm2[idx];
        k2 = (kk < k2) ? kk : k2;
    }
    d1m = fminf(d1m, __shfl_xor(d1m, 1));
    d2m = fminf(d2m, __shfl_xor(d2m, 1));
    c1m = fminf(c1m, __shfl_xor(c1m, 1));
    r3m = fminf(r3m, __shfl_xor(r3m, 1));
    { ull o = shfl_xor_u64(k2, 1); k2 = (o < k2) ? o : k2; }

    float d2sq = __uint_as_float((unsigned)(k2 >> 32));
    unsigned idxm = (unsigned)(k2 & 0xFFFFFFFFull);
    float md   = (sqrtf(d2sq) < 0.05f) ? 1.0f : 0.0f;
    float dcat = fminf(d2sq, r3m);
    float mneg = (sqrtf(dcat) > 0.2f) ? 1.0f : 0.0f;

    const float* p0 = y_hat0 + (size_t)row * 3;
    const float* p1 = y_hat1 + (size_t)row * 3;
    const float* nm = m_hat + ((size_t)b * NPTS + idxm) * 3;

    float dyn = 0.f, stat = 0.f;
    #pragma unroll
    for (int k = 0; k < 3; ++k) {
        float diff = p1[k] - p0[k];
        float e = md * (diff - nm[k]);      // masks are 0/1 -> exact
        dyn += e * e;
        float s = mneg * diff;
        stat += s * s;
    }
    float cs = (c1m < 0.1f) ? c1m : 0.f;
    float cn = (c1m < 0.1f) ? 1.f  : 0.f;
    float s1 = d1m, s2 = d2m;
    if (half) { s1 = s2 = cs = cn = dyn = stat = 0.f; }   // avoid double count

    #pragma unroll
    for (int off = 32; off > 0; off >>= 1) {
        s1  += __shfl_down(s1,  off);
        s2  += __shfl_down(s2,  off);
        cs  += __shfl_down(cs,  off);
        cn  += __shfl_down(cn,  off);
        dyn += __shfl_down(dyn, off);
        stat+= __shfl_down(stat,off);
    }
    __shared__ float sm[4][6];
    int wv = tid >> 6, ln = tid & 63;
    if (ln == 0) {
        sm[wv][0] = s1; sm[wv][1] = s2; sm[wv][2] = cs;
        sm[wv][3] = cn; sm[wv][4] = dyn; sm[wv][5] = stat;
    }
    __syncthreads();
    if (tid == 0) {
        #pragma unroll
        for (int j = 0; j < 6; ++j)
            ws[OFF_BLK + blockIdx.x * 8 + j] = sm[0][j] + sm[1][j] + sm[2][j] + sm[3][j];
    }
}

// ---------------------------------------------------------------- final combine
// 1 block x 64. Block bi covers rows [bi*128,...) -> batch = bi>>4. Deterministic
// segmented 16-lane tree, then lane 0 computes the 3 outputs.
__global__ void final_kernel(const float* __restrict__ ws, float* __restrict__ out)
{
    int lane = threadIdx.x;    // 0..63
    float v[6];
    #pragma unroll
    for (int j = 0; j < 6; ++j) v[j] = ws[OFF_BLK + lane * 8 + j];
    #pragma unroll
    for (int off = 8; off > 0; off >>= 1) {
        #pragma unroll
        for (int j = 0; j < 6; ++j) {
            float t = __shfl_down(v[j], off);
            if (((lane & 15) + off) < 16) v[j] += t;
        }
    }
    __shared__ float bs[4][6];
    if ((lane & 15) == 0) {
        #pragma unroll
        for (int j = 0; j < 6; ++j) bs[lane >> 4][j] = v[j];
    }
    __syncthreads();
    if (lane == 0) {
        float dyn = 0.f, stat = 0.f, cs = 0.f, cn = 0.f;
        for (int b = 0; b < 4; ++b) {
            float lc = bs[b][0] / (float)NPTS + bs[b][1] / (float)NPTS;
            float maskc = (lc < 0.1f) ? 1.0f : 0.0f;
            dyn  += maskc * bs[b][4];
            stat += bs[b][5];
            cs   += bs[b][2];
            cn   += bs[b][3];
        }
        const float denom = (float)(BATCH * NPTS * 3);   // 24576
        out[0] = dyn / denom;
        out[1] = stat / denom;
        out[2] = cs / fmaxf(cn, 1.0f);
    }
}

extern "C" void kernel_launch(void* const* d_in, const int* in_sizes, int n_in,
                              void* d_out, int out_size, void* d_ws, size_t ws_size,
                              hipStream_t stream)
{
    const float* x      = (const float*)d_in[0];
    const float* m_hat  = (const float*)d_in[1];
    const float* y_hat0 = (const float*)d_in[2];
    const float* y_hat1 = (const float*)d_in[3];
    float* ws  = (float*)d_ws;
    float* out = (float*)d_out;

    pairwise_kernel<<<dim3(ROWHALVES * COLCHUNKS, BATCH, 5), dim3(NT), 0, stream>>>(
        x, m_hat, y_hat0, ws);
    rowreduce_kernel<<<dim3(ROWS_TOT / 128), dim3(NT), 0, stream>>>(
        m_hat, y_hat0, y_hat1, ws);
    final_kernel<<<dim3(1), dim3(64), 0, stream>>>(ws, out);
}